// Round 3
// baseline (882.408 us; speedup 1.0000x reference)
//
#include <hip/hip_runtime.h>
#include <math.h>

typedef unsigned short ushort_t;
using short8 = __attribute__((ext_vector_type(8))) short;
using f32x4  = __attribute__((ext_vector_type(4))) float;

#define N_TOK 2048
#define DIM   1024
#define D3    3072
#define NHEAD 16
#define DH    64
#define TT    512
#define HID   4096
#define NEXP  8

__device__ __forceinline__ float bf2f(ushort_t u){
  union { unsigned int i; float f; } x; x.i = ((unsigned int)u) << 16; return x.f;
}
__device__ __forceinline__ ushort_t f2bf(float f){
  union { unsigned int i; float f; } x; x.f = f;
  unsigned int r = x.i + 0x7fffu + ((x.i >> 16) & 1u);
  return (ushort_t)(r >> 16);
}
__device__ __forceinline__ float gelu_f(float x){
  const float c = 0.7978845608028654f; // sqrt(2/pi)
  float t = tanhf(c * (x + 0.044715f * x * x * x));
  return 0.5f * x * (1.0f + t);
}

// ------- LayerNorm ---------------------------------------------------------
template<int MODE>
__global__ __launch_bounds__(256) void ln_k(const float* __restrict__ xin,
                                            const float* __restrict__ w,
                                            const float* __restrict__ b,
                                            float* __restrict__ out,
                                            ushort_t* __restrict__ outhi,
                                            ushort_t* __restrict__ outlo){
  int tok = blockIdx.x;
  int t = threadIdx.x;
  float vals[4]; float s = 0.f, ss = 0.f;
#pragma unroll
  for (int i = 0; i < 4; i++){
    int d = t + i * 256;
    float v = xin[(size_t)tok * DIM + d];
    vals[i] = v; s += v; ss += v * v;
  }
  __shared__ float rs[256], rq[256];
  rs[t] = s; rq[t] = ss; __syncthreads();
  for (int k = 128; k > 0; k >>= 1){
    if (t < k){ rs[t] += rs[t + k]; rq[t] += rq[t + k]; }
    __syncthreads();
  }
  float mu  = rs[0] * (1.0f / DIM);
  float var = rq[0] * (1.0f / DIM) - mu * mu;
  float inv = rsqrtf(var + 1e-5f);
#pragma unroll
  for (int i = 0; i < 4; i++){
    int d = t + i * 256;
    float r = (vals[i] - mu) * inv * w[d] + b[d];
    size_t idx = (size_t)tok * DIM + d;
    if (MODE == 1){
      out[idx] = r;
      outhi[idx] = f2bf(r);
    } else {
      ushort_t hv = f2bf(r);
      outhi[idx] = hv;
      outlo[idx] = f2bf(r - bf2f(hv));
    }
  }
}

// -------- Transpose-convert split: src f32 [R][C] -> hi/lo bf16 [C][R] ----
__global__ __launch_bounds__(256) void convT2(const float* __restrict__ src,
                                              ushort_t* __restrict__ dhi,
                                              ushort_t* __restrict__ dlo,
                                              int R, int C){
  __shared__ float tile[64][65];
  int r0 = blockIdx.y * 64, c0 = blockIdx.x * 64;
  int t = threadIdx.x;
  int tc = t & 15, tr = t >> 4;
#pragma unroll
  for (int i = 0; i < 4; i++){
    int r = tr + i * 16;
    float4 v = *(const float4*)&src[(size_t)(r0 + r) * C + c0 + tc * 4];
    tile[r][tc*4 + 0] = v.x; tile[r][tc*4 + 1] = v.y;
    tile[r][tc*4 + 2] = v.z; tile[r][tc*4 + 3] = v.w;
  }
  __syncthreads();
#pragma unroll
  for (int i = 0; i < 4; i++){
    int c = tr + i * 16;
    float v0 = tile[tc*4 + 0][c];
    float v1 = tile[tc*4 + 1][c];
    float v2 = tile[tc*4 + 2][c];
    float v3 = tile[tc*4 + 3][c];
    ushort4 oh, ol;
    oh.x = f2bf(v0); ol.x = f2bf(v0 - bf2f(oh.x));
    oh.y = f2bf(v1); ol.y = f2bf(v1 - bf2f(oh.y));
    oh.z = f2bf(v2); ol.z = f2bf(v2 - bf2f(oh.z));
    oh.w = f2bf(v3); ol.w = f2bf(v3 - bf2f(oh.w));
    size_t o = (size_t)(c0 + c) * R + r0 + tc * 4;
    *(ushort4*)&dhi[o] = oh;
    *(ushort4*)&dlo[o] = ol;
  }
}

// -------- Grouped transpose-convert: per-expert f32 [R][C] -> bf16 [C][R] -
__global__ __launch_bounds__(256) void convT_g(const float* __restrict__ src0,
                                               ushort_t* __restrict__ dst0,
                                               int R, int C){
  size_t eo = (size_t)blockIdx.z * R * C;
  const float* src = src0 + eo;
  ushort_t* dst = dst0 + eo;
  __shared__ float tile[64][65];
  int r0 = blockIdx.y * 64, c0 = blockIdx.x * 64;
  int t = threadIdx.x;
  int tc = t & 15, tr = t >> 4;
#pragma unroll
  for (int i = 0; i < 4; i++){
    int r = tr + i * 16;
    float4 v = *(const float4*)&src[(size_t)(r0 + r) * C + c0 + tc * 4];
    tile[r][tc*4 + 0] = v.x; tile[r][tc*4 + 1] = v.y;
    tile[r][tc*4 + 2] = v.z; tile[r][tc*4 + 3] = v.w;
  }
  __syncthreads();
#pragma unroll
  for (int i = 0; i < 4; i++){
    int c = tr + i * 16;
    ushort4 o;
    o.x = f2bf(tile[tc*4 + 0][c]);
    o.y = f2bf(tile[tc*4 + 1][c]);
    o.z = f2bf(tile[tc*4 + 2][c]);
    o.w = f2bf(tile[tc*4 + 3][c]);
    *(ushort4*)&dst[(size_t)(c0 + c) * R + r0 + tc * 4] = o;
  }
}

// -------- Split-bf16 MFMA GEMM: C = A*B + bias (+Res), near-f32 accuracy --
// 1-D grid, XCD-chunked row-fast swizzle (m204; nwg % 8 == 0).
#define TBM 128
#define TBN 128
#define TBK 32
#define LDK 40   // padded LDS row stride in bf16 elems

template<int EPI>
__global__ __launch_bounds__(256) void gemm_split(
    const ushort_t* __restrict__ Ahi, const ushort_t* __restrict__ Alo,
    const ushort_t* __restrict__ Bhi, const ushort_t* __restrict__ Blo,
    const float* __restrict__ bias,
    float* __restrict__ C, const float* __restrict__ Res,
    int Nn, int K, int mblocks)
{
  // swizzle: XCD x owns contiguous logical chunk, row varies fastest
  int q = gridDim.x >> 3;
  int L = (blockIdx.x & 7) * q + (blockIdx.x >> 3);
  int bm = (L % mblocks) * TBM;
  int bn = (L / mblocks) * TBN;
  __shared__ ushort_t Ah[TBM * LDK];
  __shared__ ushort_t Al[TBM * LDK];
  __shared__ ushort_t Bh[TBN * LDK];
  __shared__ ushort_t Bl[TBN * LDK];
  int t = threadIdx.x;
  int lane = t & 63, wave = t >> 6;
  int wm = (wave & 1) * 64, wn = (wave >> 1) * 64;

  int r0 = t >> 2, r1 = r0 + 64;
  int kc = (t & 3) * 8;
  const ushort_t* ah0 = Ahi + (size_t)(bm + r0) * K + kc;
  const ushort_t* ah1 = Ahi + (size_t)(bm + r1) * K + kc;
  const ushort_t* al0 = Alo + (size_t)(bm + r0) * K + kc;
  const ushort_t* al1 = Alo + (size_t)(bm + r1) * K + kc;
  const ushort_t* bh0 = Bhi + (size_t)(bn + r0) * K + kc;
  const ushort_t* bh1 = Bhi + (size_t)(bn + r1) * K + kc;
  const ushort_t* bl0 = Blo + (size_t)(bn + r0) * K + kc;
  const ushort_t* bl1 = Blo + (size_t)(bn + r1) * K + kc;

  f32x4 acc[4][4] = {};
  int fm = lane & 15, fk = (lane >> 4) * 8;

  // 1-deep register prefetch (tile 0)
  uint4 vah0 = *(const uint4*)(ah0);
  uint4 vah1 = *(const uint4*)(ah1);
  uint4 val0 = *(const uint4*)(al0);
  uint4 val1 = *(const uint4*)(al1);
  uint4 vbh0 = *(const uint4*)(bh0);
  uint4 vbh1 = *(const uint4*)(bh1);
  uint4 vbl0 = *(const uint4*)(bl0);
  uint4 vbl1 = *(const uint4*)(bl1);

  for (int k0 = 0; k0 < K; k0 += TBK){
    *(uint4*)&Ah[r0 * LDK + kc] = vah0;
    *(uint4*)&Ah[r1 * LDK + kc] = vah1;
    *(uint4*)&Al[r0 * LDK + kc] = val0;
    *(uint4*)&Al[r1 * LDK + kc] = val1;
    *(uint4*)&Bh[r0 * LDK + kc] = vbh0;
    *(uint4*)&Bh[r1 * LDK + kc] = vbh1;
    *(uint4*)&Bl[r0 * LDK + kc] = vbl0;
    *(uint4*)&Bl[r1 * LDK + kc] = vbl1;
    __syncthreads();
    int kn = k0 + TBK;
    if (kn < K){     // issue next-tile loads; fly during frag reads + MFMA
      vah0 = *(const uint4*)(ah0 + kn);
      vah1 = *(const uint4*)(ah1 + kn);
      val0 = *(const uint4*)(al0 + kn);
      val1 = *(const uint4*)(al1 + kn);
      vbh0 = *(const uint4*)(bh0 + kn);
      vbh1 = *(const uint4*)(bh1 + kn);
      vbl0 = *(const uint4*)(bl0 + kn);
      vbl1 = *(const uint4*)(bl1 + kn);
    }
    short8 afh[4], afl[4], bfh[4], bfl[4];
#pragma unroll
    for (int mi = 0; mi < 4; mi++){
      afh[mi] = *(const short8*)&Ah[(wm + mi*16 + fm) * LDK + fk];
      afl[mi] = *(const short8*)&Al[(wm + mi*16 + fm) * LDK + fk];
    }
#pragma unroll
    for (int nj = 0; nj < 4; nj++){
      bfh[nj] = *(const short8*)&Bh[(wn + nj*16 + fm) * LDK + fk];
      bfl[nj] = *(const short8*)&Bl[(wn + nj*16 + fm) * LDK + fk];
    }
#pragma unroll
    for (int mi = 0; mi < 4; mi++)
#pragma unroll
      for (int nj = 0; nj < 4; nj++){
        acc[mi][nj] = __builtin_amdgcn_mfma_f32_16x16x32_bf16(afh[mi], bfh[nj], acc[mi][nj], 0, 0, 0);
        acc[mi][nj] = __builtin_amdgcn_mfma_f32_16x16x32_bf16(afh[mi], bfl[nj], acc[mi][nj], 0, 0, 0);
        acc[mi][nj] = __builtin_amdgcn_mfma_f32_16x16x32_bf16(afl[mi], bfh[nj], acc[mi][nj], 0, 0, 0);
      }
    __syncthreads();
  }

#pragma unroll
  for (int mi = 0; mi < 4; mi++){
    int rowbase = bm + wm + mi*16 + (lane >> 4) * 4;
#pragma unroll
    for (int nj = 0; nj < 4; nj++){
      int n = bn + wn + nj*16 + (lane & 15);
      f32x4 v = acc[mi][nj];
#pragma unroll
      for (int rg = 0; rg < 4; rg++){
        size_t idx = (size_t)(rowbase + rg) * Nn + n;
        float val = v[rg] + bias[n];
        if (EPI == 1) val += Res[idx];
        C[idx] = val;
      }
    }
  }
}

// ---------------- Attention scores: S[bh,q,k] = (Q·K)/8 -------------------
__global__ __launch_bounds__(256) void scores_k(const float* __restrict__ qkv,
                                                float* __restrict__ S){
  int bh = blockIdx.z; int b = bh >> 4, h = bh & 15;
  int q0 = blockIdx.y * 64, k0 = blockIdx.x * 64;
  __shared__ float Qs[64][68];
  __shared__ float Ks[64][68];
  int t = threadIdx.x;
  int r = t >> 2, dp = (t & 3) * 16;
  {
    const float* qp = qkv + (size_t)(b * TT + q0 + r) * D3 + h * DH + dp;
    const float* kp = qkv + (size_t)(b * TT + k0 + r) * D3 + DIM + h * DH + dp;
#pragma unroll
    for (int c = 0; c < 4; c++){
      float4 qv = *(const float4*)(qp + c * 4);
      float4 kv = *(const float4*)(kp + c * 4);
      Qs[dp + c*4 + 0][r] = qv.x; Qs[dp + c*4 + 1][r] = qv.y;
      Qs[dp + c*4 + 2][r] = qv.z; Qs[dp + c*4 + 3][r] = qv.w;
      Ks[dp + c*4 + 0][r] = kv.x; Ks[dp + c*4 + 1][r] = kv.y;
      Ks[dp + c*4 + 2][r] = kv.z; Ks[dp + c*4 + 3][r] = kv.w;
    }
  }
  __syncthreads();
  int tx = t & 15, ty = t >> 4;
  float acc[4][4] = {};
#pragma unroll 8
  for (int d = 0; d < 64; d++){
    float4 qv = *(const float4*)&Qs[d][ty * 4];
    float4 kv = *(const float4*)&Ks[d][tx * 4];
    float qa[4] = {qv.x,qv.y,qv.z,qv.w};
    float ka[4] = {kv.x,kv.y,kv.z,kv.w};
#pragma unroll
    for (int i = 0; i < 4; i++)
#pragma unroll
      for (int j = 0; j < 4; j++)
        acc[i][j] += qa[i] * ka[j];
  }
#pragma unroll
  for (int i = 0; i < 4; i++)
#pragma unroll
    for (int j = 0; j < 4; j++)
      S[((size_t)bh * TT + q0 + ty*4 + i) * TT + k0 + tx*4 + j] = acc[i][j] * 0.125f;
}

// ---------------- Softmax over rows of 512 --------------------------------
__global__ __launch_bounds__(256) void softmax_k(float* __restrict__ S){
  size_t row = blockIdx.x;
  float* p = S + row * TT;
  int t = threadIdx.x;
  float v0 = p[t], v1 = p[t + 256];
  __shared__ float red[256];
  red[t] = fmaxf(v0, v1); __syncthreads();
  for (int k = 128; k > 0; k >>= 1){ if (t < k) red[t] = fmaxf(red[t], red[t + k]); __syncthreads(); }
  float m = red[0]; __syncthreads();
  float e0 = expf(v0 - m), e1 = expf(v1 - m);
  red[t] = e0 + e1; __syncthreads();
  for (int k = 128; k > 0; k >>= 1){ if (t < k) red[t] += red[t + k]; __syncthreads(); }
  float inv = 1.0f / red[0];
  p[t] = e0 * inv; p[t + 256] = e1 * inv;
}

// ------- ctx = P @ V; write bf16 hi/lo [2048][1024] for split MFMA --------
__global__ __launch_bounds__(256) void ctx_k(const float* __restrict__ P,
                                             const float* __restrict__ qkv,
                                             ushort_t* __restrict__ chi,
                                             ushort_t* __restrict__ clo){
  int bh = blockIdx.y; int b = bh >> 4, h = bh & 15;
  int q0 = blockIdx.x * 64;
  __shared__ float Ps[16][68];
  __shared__ float Vs[16][68];
  int t = threadIdx.x;
  int tx = t & 15, ty = t >> 4;
  int pq = t >> 2, pk = (t & 3) * 4;
  int vk = t >> 4, vd = (t & 15) * 4;
  float acc[4][4] = {};
  for (int kk = 0; kk < TT; kk += 16){
    float4 pv = *(const float4*)&P[((size_t)bh * TT + q0 + pq) * TT + kk + pk];
    Ps[pk + 0][pq] = pv.x; Ps[pk + 1][pq] = pv.y;
    Ps[pk + 2][pq] = pv.z; Ps[pk + 3][pq] = pv.w;
    float4 vv = *(const float4*)&qkv[(size_t)(b * TT + kk + vk) * D3 + 2 * DIM + h * DH + vd];
    Vs[vk][vd + 0] = vv.x; Vs[vk][vd + 1] = vv.y;
    Vs[vk][vd + 2] = vv.z; Vs[vk][vd + 3] = vv.w;
    __syncthreads();
#pragma unroll
    for (int k = 0; k < 16; k++){
      float4 a = *(const float4*)&Ps[k][ty * 4];
      float4 bb = *(const float4*)&Vs[k][tx * 4];
      float aa[4] = {a.x,a.y,a.z,a.w};
      float bv[4] = {bb.x,bb.y,bb.z,bb.w};
#pragma unroll
      for (int i = 0; i < 4; i++)
#pragma unroll
        for (int j = 0; j < 4; j++)
          acc[i][j] += aa[i] * bv[j];
    }
    __syncthreads();
  }
#pragma unroll
  for (int i = 0; i < 4; i++)
#pragma unroll
    for (int j = 0; j < 4; j++){
      float v = acc[i][j];
      size_t idx = (size_t)(b * TT + q0 + ty*4 + i) * DIM + h * DH + tx*4 + j;
      ushort_t hv = f2bf(v);
      chi[idx] = hv;
      clo[idx] = f2bf(v - bf2f(hv));
    }
}

// -------- Gate (exact f32) + top-2 renorm weights -------------------------
__global__ __launch_bounds__(256) void gate_k(const float* __restrict__ ln2f,
                                              const float* __restrict__ wg,
                                              float* __restrict__ we){
  int tok = blockIdx.x * 4 + (threadIdx.x >> 6);
  int lane = threadIdx.x & 63;
  float acc[8] = {};
  for (int d = lane; d < DIM; d += 64){
    float x = ln2f[(size_t)tok * DIM + d];
    float4 w0 = *(const float4*)&wg[d * 8];
    float4 w1v = *(const float4*)&wg[d * 8 + 4];
    float wv[8] = {w0.x,w0.y,w0.z,w0.w,w1v.x,w1v.y,w1v.z,w1v.w};
#pragma unroll
    for (int e = 0; e < 8; e++) acc[e] += x * wv[e];
  }
#pragma unroll
  for (int off = 32; off > 0; off >>= 1){
#pragma unroll
    for (int e = 0; e < 8; e++) acc[e] += __shfl_down(acc[e], off);
  }
  if (lane == 0){
    float m = acc[0];
    for (int e = 1; e < 8; e++) m = fmaxf(m, acc[e]);
    float pr[8], s = 0.f;
    for (int e = 0; e < 8; e++){ pr[e] = expf(acc[e] - m); s += pr[e]; }
    for (int e = 0; e < 8; e++) pr[e] /= s;
    int i0 = 0;
    for (int e = 1; e < 8; e++) if (pr[e] > pr[i0]) i0 = e;
    int i1 = (i0 == 0) ? 1 : 0;
    for (int e = 0; e < 8; e++) if (e != i0 && pr[e] > pr[i1]) i1 = e;
    float sm = pr[i0] + pr[i1];
    for (int e = 0; e < 8; e++)
      we[(size_t)tok * 8 + e] = (e == i0) ? pr[i0] / sm : ((e == i1) ? pr[i1] / sm : 0.f);
  }
}

// -------- Routing: bucket tokens per expert (device-side counts) ----------
__global__ __launch_bounds__(256) void route_k(const float* __restrict__ we,
                                               int* __restrict__ cnt,
                                               int* __restrict__ gidx,
                                               float* __restrict__ gw){
  int tok = blockIdx.x * 256 + threadIdx.x;
#pragma unroll
  for (int e = 0; e < NEXP; e++){
    float w = we[(size_t)tok * NEXP + e];
    if (w > 0.f){
      int p = atomicAdd(&cnt[e], 1);
      gidx[e * N_TOK + p] = tok;
      gw[e * N_TOK + p] = w;
    }
  }
}

// -------- Exclusive scan of 8 expert counts -------------------------------
__global__ void scan_k(const int* __restrict__ cnt, int* __restrict__ off){
  if (threadIdx.x == 0){
    int s = 0;
    for (int e = 0; e < NEXP; e++){ off[e] = s; s += cnt[e]; }
  }
}

// -------- Grouped MFMA bf16 expert GEMM (all experts, one 1-D launch) -----
// rid = blockIdx.x; expert e = rid&7 (-> XCD e), s = rid>>3 row-fast.
// EPI 0: K=DIM, 512 slots/expert = 16 rows x 32 cols. gather rows; gelu->bf16.
// EPI 1: K=HID split 4x1024, 512 slots = 16 rows x 8 cols x 4 ksplit.
//        scatter atomicAdd(gw*(acc + [ks==0]bias)).
template<int EPI>
__global__ __launch_bounds__(256) void moe_gemm_g(
    const ushort_t* __restrict__ A,      // EPI0: ln2bf [N_TOK][K]; EPI1: h1e [4096][K]
    const ushort_t* __restrict__ BT_all, // bf16 [E][N][K]
    const float* __restrict__ bias_all,  // [E][N]
    ushort_t* __restrict__ Obf,          // EPI0 out: h1e [4096][Nn]
    float* __restrict__ Of,              // EPI1 out: accb [N_TOK][Nn]
    const int* __restrict__ gidx_all,    // [E][N_TOK]
    const float* __restrict__ gw_all,    // [E][N_TOK]
    const int* __restrict__ cnt,         // [E]
    const int* __restrict__ off,         // [E] exclusive scan
    int Nn)
{
  int rid = blockIdx.x;
  int e = rid & 7;
  int s = rid >> 3;
  int c = cnt[e];
  int bm = (s & 15) * TBM;
  if (bm >= c) return;
  int col, ks;
  if (EPI == 0){ col = s >> 4; ks = 0; }
  else         { col = (s >> 4) & 7; ks = s >> 7; }
  const int K = (EPI == 0) ? DIM : HID;
  int kbase = ks * 1024;                 // 1024-wide K window, 32 steps
  int bn = col * TBN;
  const int* gidx = gidx_all + e * N_TOK;
  const float* gwp = gw_all + e * N_TOK;
  const ushort_t* BT = BT_all + (size_t)e * Nn * K;
  const float* bias = bias_all + (size_t)e * Nn;
  int obase = off[e];

  __shared__ ushort_t As[TBM * LDK];
  __shared__ ushort_t Bs[TBN * LDK];
  int t = threadIdx.x;
  int lane = t & 63, wave = t >> 6;
  int wm = (wave & 1) * 64, wn = (wave >> 1) * 64;

  int r0 = t >> 2, r1 = r0 + 64;
  int kc = (t & 3) * 8;
  size_t ga0, ga1;
  if (EPI == 0){
    int g0 = bm + r0, g1 = bm + r1;
    ga0 = (size_t)((g0 < c) ? gidx[g0] : gidx[bm]);
    ga1 = (size_t)((g1 < c) ? gidx[g1] : gidx[bm]);
  } else {
    int mx = 2 * N_TOK - 1;
    int g0 = obase + bm + r0; if (g0 > mx) g0 = mx;
    int g1 = obase + bm + r1; if (g1 > mx) g1 = mx;
    ga0 = (size_t)g0; ga1 = (size_t)g1;
  }
  const ushort_t* a0p = A + ga0 * K + kbase + kc;
  const ushort_t* a1p = A + ga1 * K + kbase + kc;
  const ushort_t* b0p = BT + (size_t)(bn + r0) * K + kbase + kc;
  const ushort_t* b1p = BT + (size_t)(bn + r1) * K + kbase + kc;

  f32x4 acc[4][4] = {};
  int fm = lane & 15, fk = (lane >> 4) * 8;

  // 2-deep register prefetch: slot A = tile it, slot B = tile it+1
  uint4 Aa0 = *(const uint4*)(a0p);
  uint4 Aa1 = *(const uint4*)(a1p);
  uint4 Ba0 = *(const uint4*)(b0p);
  uint4 Ba1 = *(const uint4*)(b1p);
  uint4 Ab0 = *(const uint4*)(a0p + TBK);
  uint4 Ab1 = *(const uint4*)(a1p + TBK);
  uint4 Bb0 = *(const uint4*)(b0p + TBK);
  uint4 Bb1 = *(const uint4*)(b1p + TBK);

  const int KSTEPS = 32;
  for (int it = 0; it < KSTEPS; it += 2){
    // ---- even tile (slot A) ----
    *(uint4*)&As[r0 * LDK + kc] = Aa0;
    *(uint4*)&As[r1 * LDK + kc] = Aa1;
    *(uint4*)&Bs[r0 * LDK + kc] = Ba0;
    *(uint4*)&Bs[r1 * LDK + kc] = Ba1;
    __syncthreads();
    if (it + 2 < KSTEPS){
      int kn = (it + 2) * TBK;
      Aa0 = *(const uint4*)(a0p + kn);
      Aa1 = *(const uint4*)(a1p + kn);
      Ba0 = *(const uint4*)(b0p + kn);
      Ba1 = *(const uint4*)(b1p + kn);
    }
    {
      short8 af[4], bfr[4];
#pragma unroll
      for (int mi = 0; mi < 4; mi++)
        af[mi] = *(const short8*)&As[(wm + mi*16 + fm) * LDK + fk];
#pragma unroll
      for (int nj = 0; nj < 4; nj++)
        bfr[nj] = *(const short8*)&Bs[(wn + nj*16 + fm) * LDK + fk];
#pragma unroll
      for (int mi = 0; mi < 4; mi++)
#pragma unroll
        for (int nj = 0; nj < 4; nj++)
          acc[mi][nj] = __builtin_amdgcn_mfma_f32_16x16x32_bf16(af[mi], bfr[nj], acc[mi][nj], 0, 0, 0);
    }
    __syncthreads();
    // ---- odd tile (slot B) ----
    *(uint4*)&As[r0 * LDK + kc] = Ab0;
    *(uint4*)&As[r1 * LDK + kc] = Ab1;
    *(uint4*)&Bs[r0 * LDK + kc] = Bb0;
    *(uint4*)&Bs[r1 * LDK + kc] = Bb1;
    __syncthreads();
    if (it + 3 < KSTEPS){
      int kn = (it + 3) * TBK;
      Ab0 = *(const uint4*)(a0p + kn);
      Ab1 = *(const uint4*)(a1p + kn);
      Bb0 = *(const uint4*)(b0p + kn);
      Bb1 = *(const uint4*)(b1p + kn);
    }
    {
      short8 af[4], bfr[4];
#pragma unroll
      for (int mi = 0; mi < 4; mi++)
        af[mi] = *(const short8*)&As[(wm + mi*16 + fm) * LDK + fk];
#pragma unroll
      for (int nj = 0; nj < 4; nj++)
        bfr[nj] = *(const short8*)&Bs[(wn + nj*16 + fm) * LDK + fk];
#pragma unroll
      for (int mi = 0; mi < 4; mi++)
#pragma unroll
        for (int nj = 0; nj < 4; nj++)
          acc[mi][nj] = __builtin_amdgcn_mfma_f32_16x16x32_bf16(af[mi], bfr[nj], acc[mi][nj], 0, 0, 0);
    }
    __syncthreads();
  }

  // epilogue: C/D layout col=lane&15, row=(lane>>4)*4+reg  [m89-verified]
#pragma unroll
  for (int mi = 0; mi < 4; mi++){
    int rowbase = bm + wm + mi*16 + (lane >> 4) * 4;
#pragma unroll
    for (int nj = 0; nj < 4; nj++){
      int n = bn + wn + nj*16 + (lane & 15);
      f32x4 v = acc[mi][nj];
#pragma unroll
      for (int rg = 0; rg < 4; rg++){
        int r = rowbase + rg;
        if (r < c){
          if (EPI == 0){
            float val = v[rg] + bias[n];
            Obf[(size_t)(obase + r) * Nn + n] = f2bf(gelu_f(val));
          } else {
            float val = v[rg];
            if (ks == 0) val += bias[n];
            int tok = gidx[r];
            atomicAdd(&Of[(size_t)tok * Nn + n], gwp[r] * val);
          }
        }
      }
    }
  }
}

// ---------------- Final: out = h + moe_acc (f32) --------------------------
__global__ __launch_bounds__(256) void final_k(const float* __restrict__ h,
                                               const float* __restrict__ acc,
                                               float* __restrict__ out){
  size_t i = (size_t)blockIdx.x * 256 + threadIdx.x;
  out[i] = h[i] + acc[i];
}

extern "C" void kernel_launch(void* const* d_in, const int* in_sizes, int n_in,
                              void* d_out, int out_size, void* d_ws, size_t ws_size,
                              hipStream_t stream){
  const float* x     = (const float*)d_in[0];
  const float* ln1w  = (const float*)d_in[1];
  const float* ln1b  = (const float*)d_in[2];
  const float* ln2w  = (const float*)d_in[3];
  const float* ln2b  = (const float*)d_in[4];
  const float* wqkv  = (const float*)d_in[5];
  const float* bqkv  = (const float*)d_in[6];
  const float* wo    = (const float*)d_in[7];
  const float* bo    = (const float*)d_in[8];
  const float* wgate = (const float*)d_in[9];
  const float* w1    = (const float*)d_in[10];
  const float* b1    = (const float*)d_in[11];
  const float* w2    = (const float*)d_in[12];
  const float* b2    = (const float*)d_in[13];

  // Workspace map (121 MB peak, lifetimes disjoint — see round-2 notes):
  char* ws = (char*)d_ws;
  const size_t MB = 1024 * 1024;
  float*    hbuf  = (float*)(ws + 0 * MB);
  ushort_t* ln1hi = (ushort_t*)(ws + 0 * MB);
  ushort_t* ln1lo = (ushort_t*)(ws + 4 * MB);
  float*    accb  = (float*)(ws + 8 * MB);
  ushort_t* wqkvThi = (ushort_t*)(ws + 8 * MB);             // 6 MB
  ushort_t* wqkvTlo = (ushort_t*)(ws + 14 * MB);            // 6 MB
  ushort_t* ln2bf = (ushort_t*)(ws + 16 * MB);              // 4 MB
  ushort_t* h1e   = (ushort_t*)(ws + 20 * MB);              // 32 MB
  float*    qkv   = (float*)(ws + 20 * MB);                 // 24 MB
  float*    ln2f  = (float*)(ws + 24 * MB);                 // 8 MB
  ushort_t* ctxhi = (ushort_t*)(ws + 44 * MB);
  ushort_t* ctxlo = (ushort_t*)(ws + 48 * MB);
  ushort_t* woThi = (ushort_t*)(ws + 52 * MB);              // 2 MB
  ushort_t* woTlo = (ushort_t*)(ws + 54 * MB);              // 2 MB
  float*    sc    = (float*)(ws + 56 * MB);                 // 64 MB
  ushort_t* wTe   = (ushort_t*)(ws + 56 * MB);              // 64 MB
  float*    webuf = (float*)(ws + 120 * MB);                // 64 KB
  int*      cnt   = (int*)  (ws + 120 * MB + 256 * 1024);   // 32 B
  int*      off   = (int*)  (ws + 120 * MB + 260 * 1024);   // 32 B
  int*      bidx  = (int*)  (ws + 120 * MB + 320 * 1024);   // 64 KB
  float*    bw    = (float*)(ws + 120 * MB + 448 * 1024);   // 64 KB

  // ---- attention path: split-bf16 MFMA GEMMs (near-f32 accuracy) ----
  ln_k<2><<<N_TOK, 256, 0, stream>>>(x, ln1w, ln1b, nullptr, ln1hi, ln1lo);
  convT2<<<dim3(D3 / 64, DIM / 64), 256, 0, stream>>>(wqkv, wqkvThi, wqkvTlo, DIM, D3);
  gemm_split<0><<<(N_TOK / TBM) * (D3 / TBN), 256, 0, stream>>>(
      ln1hi, ln1lo, wqkvThi, wqkvTlo, bqkv, qkv, nullptr, D3, DIM, N_TOK / TBM);
  scores_k<<<dim3(8, 8, 64), 256, 0, stream>>>(qkv, sc);
  softmax_k<<<64 * TT, 256, 0, stream>>>(sc);
  ctx_k<<<dim3(8, 64), 256, 0, stream>>>(sc, qkv, ctxhi, ctxlo);
  // sc dead -> convert ALL expert w1 into wTe (one launch)
  convT_g<<<dim3(HID / 64, DIM / 64, NEXP), 256, 0, stream>>>(w1, wTe, DIM, HID);
  convT2<<<dim3(DIM / 64, DIM / 64), 256, 0, stream>>>(wo, woThi, woTlo, DIM, DIM);
  gemm_split<1><<<(N_TOK / TBM) * (DIM / TBN), 256, 0, stream>>>(
      ctxhi, ctxlo, woThi, woTlo, bo, hbuf, x, DIM, DIM, N_TOK / TBM);
  ln_k<1><<<N_TOK, 256, 0, stream>>>(hbuf, ln2w, ln2b, ln2f, ln2bf, nullptr);
  gate_k<<<N_TOK / 4, 256, 0, stream>>>(ln2f, wgate, webuf);

  // ---- routed MoE: grouped 1-D launches, expert-per-XCD swizzle ----
  hipMemsetAsync(cnt, 0, 32, stream);
  hipMemsetAsync(accb, 0, (size_t)N_TOK * DIM * 4, stream);
  route_k<<<N_TOK / 256, 256, 0, stream>>>(webuf, cnt, bidx, bw);
  scan_k<<<1, 64, 0, stream>>>(cnt, off);
  // GEMM1: 8 experts x (16 rows x 32 cols) = 4096 blocks
  moe_gemm_g<0><<<NEXP * 16 * (HID / TBN), 256, 0, stream>>>(
      ln2bf, wTe, b1, h1e, nullptr, bidx, bw, cnt, off, HID);
  convT_g<<<dim3(DIM / 64, HID / 64, NEXP), 256, 0, stream>>>(w2, wTe, HID, DIM);
  // GEMM2: 8 experts x (16 rows x 8 cols x 4 ksplit) = 4096 blocks
  moe_gemm_g<1><<<NEXP * 16 * (DIM / TBN) * 4, 256, 0, stream>>>(
      h1e, wTe, b2, nullptr, accb, bidx, bw, cnt, off, DIM);
  final_k<<<(N_TOK * DIM) / 256, 256, 0, stream>>>(hbuf, accb, (float*)d_out);
}

// Round 4
// 823.111 us; speedup vs baseline: 1.0720x; 1.0720x over previous
//
#include <hip/hip_runtime.h>
#include <math.h>

typedef unsigned short ushort_t;
using short8 = __attribute__((ext_vector_type(8))) short;
using f32x4  = __attribute__((ext_vector_type(4))) float;

#define N_TOK 2048
#define DIM   1024
#define D3    3072
#define NHEAD 16
#define DH    64
#define TT    512
#define HID   4096
#define NEXP  8

__device__ __forceinline__ float bf2f(ushort_t u){
  union { unsigned int i; float f; } x; x.i = ((unsigned int)u) << 16; return x.f;
}
__device__ __forceinline__ ushort_t f2bf(float f){
  union { unsigned int i; float f; } x; x.f = f;
  unsigned int r = x.i + 0x7fffu + ((x.i >> 16) & 1u);
  return (ushort_t)(r >> 16);
}
__device__ __forceinline__ float gelu_f(float x){
  const float c = 0.7978845608028654f; // sqrt(2/pi)
  float t = tanhf(c * (x + 0.044715f * x * x * x));
  return 0.5f * x * (1.0f + t);
}

// ------- LayerNorm ---------------------------------------------------------
template<int MODE>
__global__ __launch_bounds__(256) void ln_k(const float* __restrict__ xin,
                                            const float* __restrict__ w,
                                            const float* __restrict__ b,
                                            float* __restrict__ out,
                                            ushort_t* __restrict__ outhi,
                                            ushort_t* __restrict__ outlo){
  int tok = blockIdx.x;
  int t = threadIdx.x;
  float vals[4]; float s = 0.f, ss = 0.f;
#pragma unroll
  for (int i = 0; i < 4; i++){
    int d = t + i * 256;
    float v = xin[(size_t)tok * DIM + d];
    vals[i] = v; s += v; ss += v * v;
  }
  __shared__ float rs[256], rq[256];
  rs[t] = s; rq[t] = ss; __syncthreads();
  for (int k = 128; k > 0; k >>= 1){
    if (t < k){ rs[t] += rs[t + k]; rq[t] += rq[t + k]; }
    __syncthreads();
  }
  float mu  = rs[0] * (1.0f / DIM);
  float var = rq[0] * (1.0f / DIM) - mu * mu;
  float inv = rsqrtf(var + 1e-5f);
#pragma unroll
  for (int i = 0; i < 4; i++){
    int d = t + i * 256;
    float r = (vals[i] - mu) * inv * w[d] + b[d];
    size_t idx = (size_t)tok * DIM + d;
    if (MODE == 1){
      out[idx] = r;
      outhi[idx] = f2bf(r);
    } else {
      ushort_t hv = f2bf(r);
      outhi[idx] = hv;
      outlo[idx] = f2bf(r - bf2f(hv));
    }
  }
}

// -------- Transpose-convert split: src f32 [R][C] -> hi/lo bf16 [C][R] ----
__global__ __launch_bounds__(256) void convT2(const float* __restrict__ src,
                                              ushort_t* __restrict__ dhi,
                                              ushort_t* __restrict__ dlo,
                                              int R, int C){
  __shared__ float tile[64][65];
  int r0 = blockIdx.y * 64, c0 = blockIdx.x * 64;
  int t = threadIdx.x;
  int tc = t & 15, tr = t >> 4;
#pragma unroll
  for (int i = 0; i < 4; i++){
    int r = tr + i * 16;
    float4 v = *(const float4*)&src[(size_t)(r0 + r) * C + c0 + tc * 4];
    tile[r][tc*4 + 0] = v.x; tile[r][tc*4 + 1] = v.y;
    tile[r][tc*4 + 2] = v.z; tile[r][tc*4 + 3] = v.w;
  }
  __syncthreads();
#pragma unroll
  for (int i = 0; i < 4; i++){
    int c = tr + i * 16;
    float v0 = tile[tc*4 + 0][c];
    float v1 = tile[tc*4 + 1][c];
    float v2 = tile[tc*4 + 2][c];
    float v3 = tile[tc*4 + 3][c];
    ushort4 oh, ol;
    oh.x = f2bf(v0); ol.x = f2bf(v0 - bf2f(oh.x));
    oh.y = f2bf(v1); ol.y = f2bf(v1 - bf2f(oh.y));
    oh.z = f2bf(v2); ol.z = f2bf(v2 - bf2f(oh.z));
    oh.w = f2bf(v3); ol.w = f2bf(v3 - bf2f(oh.w));
    size_t o = (size_t)(c0 + c) * R + r0 + tc * 4;
    *(ushort4*)&dhi[o] = oh;
    *(ushort4*)&dlo[o] = ol;
  }
}

// -------- Grouped transpose-convert: per-expert f32 [R][C] -> bf16 [C][R] -
__global__ __launch_bounds__(256) void convT_g(const float* __restrict__ src0,
                                               ushort_t* __restrict__ dst0,
                                               int R, int C){
  size_t eo = (size_t)blockIdx.z * R * C;
  const float* src = src0 + eo;
  ushort_t* dst = dst0 + eo;
  __shared__ float tile[64][65];
  int r0 = blockIdx.y * 64, c0 = blockIdx.x * 64;
  int t = threadIdx.x;
  int tc = t & 15, tr = t >> 4;
#pragma unroll
  for (int i = 0; i < 4; i++){
    int r = tr + i * 16;
    float4 v = *(const float4*)&src[(size_t)(r0 + r) * C + c0 + tc * 4];
    tile[r][tc*4 + 0] = v.x; tile[r][tc*4 + 1] = v.y;
    tile[r][tc*4 + 2] = v.z; tile[r][tc*4 + 3] = v.w;
  }
  __syncthreads();
#pragma unroll
  for (int i = 0; i < 4; i++){
    int c = tr + i * 16;
    ushort4 o;
    o.x = f2bf(tile[tc*4 + 0][c]);
    o.y = f2bf(tile[tc*4 + 1][c]);
    o.z = f2bf(tile[tc*4 + 2][c]);
    o.w = f2bf(tile[tc*4 + 3][c]);
    *(ushort4*)&dst[(size_t)(c0 + c) * R + r0 + tc * 4] = o;
  }
}

// -------- Split-bf16 MFMA GEMM: C = A*B + bias (+Res), near-f32 accuracy --
// 1-D grid, XCD-chunked row-fast swizzle (m204; nwg % 8 == 0).
#define TBM 128
#define TBN 128
#define TBK 32
#define LDK 40   // padded LDS row stride in bf16 elems

template<int EPI>
__global__ __launch_bounds__(256) void gemm_split(
    const ushort_t* __restrict__ Ahi, const ushort_t* __restrict__ Alo,
    const ushort_t* __restrict__ Bhi, const ushort_t* __restrict__ Blo,
    const float* __restrict__ bias,
    float* __restrict__ C, const float* __restrict__ Res,
    int Nn, int K, int mblocks)
{
  int q = gridDim.x >> 3;
  int L = (blockIdx.x & 7) * q + (blockIdx.x >> 3);
  int bm = (L % mblocks) * TBM;
  int bn = (L / mblocks) * TBN;
  __shared__ ushort_t Ah[TBM * LDK];
  __shared__ ushort_t Al[TBM * LDK];
  __shared__ ushort_t Bh[TBN * LDK];
  __shared__ ushort_t Bl[TBN * LDK];
  int t = threadIdx.x;
  int lane = t & 63, wave = t >> 6;
  int wm = (wave & 1) * 64, wn = (wave >> 1) * 64;

  int r0 = t >> 2, r1 = r0 + 64;
  int kc = (t & 3) * 8;
  const ushort_t* ah0 = Ahi + (size_t)(bm + r0) * K + kc;
  const ushort_t* ah1 = Ahi + (size_t)(bm + r1) * K + kc;
  const ushort_t* al0 = Alo + (size_t)(bm + r0) * K + kc;
  const ushort_t* al1 = Alo + (size_t)(bm + r1) * K + kc;
  const ushort_t* bh0 = Bhi + (size_t)(bn + r0) * K + kc;
  const ushort_t* bh1 = Bhi + (size_t)(bn + r1) * K + kc;
  const ushort_t* bl0 = Blo + (size_t)(bn + r0) * K + kc;
  const ushort_t* bl1 = Blo + (size_t)(bn + r1) * K + kc;

  f32x4 acc[4][4] = {};
  int fm = lane & 15, fk = (lane >> 4) * 8;

  uint4 vah0 = *(const uint4*)(ah0);
  uint4 vah1 = *(const uint4*)(ah1);
  uint4 val0 = *(const uint4*)(al0);
  uint4 val1 = *(const uint4*)(al1);
  uint4 vbh0 = *(const uint4*)(bh0);
  uint4 vbh1 = *(const uint4*)(bh1);
  uint4 vbl0 = *(const uint4*)(bl0);
  uint4 vbl1 = *(const uint4*)(bl1);

  for (int k0 = 0; k0 < K; k0 += TBK){
    *(uint4*)&Ah[r0 * LDK + kc] = vah0;
    *(uint4*)&Ah[r1 * LDK + kc] = vah1;
    *(uint4*)&Al[r0 * LDK + kc] = val0;
    *(uint4*)&Al[r1 * LDK + kc] = val1;
    *(uint4*)&Bh[r0 * LDK + kc] = vbh0;
    *(uint4*)&Bh[r1 * LDK + kc] = vbh1;
    *(uint4*)&Bl[r0 * LDK + kc] = vbl0;
    *(uint4*)&Bl[r1 * LDK + kc] = vbl1;
    __syncthreads();
    int kn = k0 + TBK;
    if (kn < K){
      vah0 = *(const uint4*)(ah0 + kn);
      vah1 = *(const uint4*)(ah1 + kn);
      val0 = *(const uint4*)(al0 + kn);
      val1 = *(const uint4*)(al1 + kn);
      vbh0 = *(const uint4*)(bh0 + kn);
      vbh1 = *(const uint4*)(bh1 + kn);
      vbl0 = *(const uint4*)(bl0 + kn);
      vbl1 = *(const uint4*)(bl1 + kn);
    }
    short8 afh[4], afl[4], bfh[4], bfl[4];
#pragma unroll
    for (int mi = 0; mi < 4; mi++){
      afh[mi] = *(const short8*)&Ah[(wm + mi*16 + fm) * LDK + fk];
      afl[mi] = *(const short8*)&Al[(wm + mi*16 + fm) * LDK + fk];
    }
#pragma unroll
    for (int nj = 0; nj < 4; nj++){
      bfh[nj] = *(const short8*)&Bh[(wn + nj*16 + fm) * LDK + fk];
      bfl[nj] = *(const short8*)&Bl[(wn + nj*16 + fm) * LDK + fk];
    }
#pragma unroll
    for (int mi = 0; mi < 4; mi++)
#pragma unroll
      for (int nj = 0; nj < 4; nj++){
        acc[mi][nj] = __builtin_amdgcn_mfma_f32_16x16x32_bf16(afh[mi], bfh[nj], acc[mi][nj], 0, 0, 0);
        acc[mi][nj] = __builtin_amdgcn_mfma_f32_16x16x32_bf16(afh[mi], bfl[nj], acc[mi][nj], 0, 0, 0);
        acc[mi][nj] = __builtin_amdgcn_mfma_f32_16x16x32_bf16(afl[mi], bfh[nj], acc[mi][nj], 0, 0, 0);
      }
    __syncthreads();
  }

#pragma unroll
  for (int mi = 0; mi < 4; mi++){
    int rowbase = bm + wm + mi*16 + (lane >> 4) * 4;
#pragma unroll
    for (int nj = 0; nj < 4; nj++){
      int n = bn + wn + nj*16 + (lane & 15);
      f32x4 v = acc[mi][nj];
#pragma unroll
      for (int rg = 0; rg < 4; rg++){
        size_t idx = (size_t)(rowbase + rg) * Nn + n;
        float val = v[rg] + bias[n];
        if (EPI == 1) val += Res[idx];
        C[idx] = val;
      }
    }
  }
}

// ---------------- Attention scores: S[bh,q,k] = (Q·K)/8 -------------------
__global__ __launch_bounds__(256) void scores_k(const float* __restrict__ qkv,
                                                float* __restrict__ S){
  int bh = blockIdx.z; int b = bh >> 4, h = bh & 15;
  int q0 = blockIdx.y * 64, k0 = blockIdx.x * 64;
  __shared__ float Qs[64][68];
  __shared__ float Ks[64][68];
  int t = threadIdx.x;
  int r = t >> 2, dp = (t & 3) * 16;
  {
    const float* qp = qkv + (size_t)(b * TT + q0 + r) * D3 + h * DH + dp;
    const float* kp = qkv + (size_t)(b * TT + k0 + r) * D3 + DIM + h * DH + dp;
#pragma unroll
    for (int c = 0; c < 4; c++){
      float4 qv = *(const float4*)(qp + c * 4);
      float4 kv = *(const float4*)(kp + c * 4);
      Qs[dp + c*4 + 0][r] = qv.x; Qs[dp + c*4 + 1][r] = qv.y;
      Qs[dp + c*4 + 2][r] = qv.z; Qs[dp + c*4 + 3][r] = qv.w;
      Ks[dp + c*4 + 0][r] = kv.x; Ks[dp + c*4 + 1][r] = kv.y;
      Ks[dp + c*4 + 2][r] = kv.z; Ks[dp + c*4 + 3][r] = kv.w;
    }
  }
  __syncthreads();
  int tx = t & 15, ty = t >> 4;
  float acc[4][4] = {};
#pragma unroll 8
  for (int d = 0; d < 64; d++){
    float4 qv = *(const float4*)&Qs[d][ty * 4];
    float4 kv = *(const float4*)&Ks[d][tx * 4];
    float qa[4] = {qv.x,qv.y,qv.z,qv.w};
    float ka[4] = {kv.x,kv.y,kv.z,kv.w};
#pragma unroll
    for (int i = 0; i < 4; i++)
#pragma unroll
      for (int j = 0; j < 4; j++)
        acc[i][j] += qa[i] * ka[j];
  }
#pragma unroll
  for (int i = 0; i < 4; i++)
#pragma unroll
    for (int j = 0; j < 4; j++)
      S[((size_t)bh * TT + q0 + ty*4 + i) * TT + k0 + tx*4 + j] = acc[i][j] * 0.125f;
}

// ---------------- Softmax over rows of 512 --------------------------------
__global__ __launch_bounds__(256) void softmax_k(float* __restrict__ S){
  size_t row = blockIdx.x;
  float* p = S + row * TT;
  int t = threadIdx.x;
  float v0 = p[t], v1 = p[t + 256];
  __shared__ float red[256];
  red[t] = fmaxf(v0, v1); __syncthreads();
  for (int k = 128; k > 0; k >>= 1){ if (t < k) red[t] = fmaxf(red[t], red[t + k]); __syncthreads(); }
  float m = red[0]; __syncthreads();
  float e0 = expf(v0 - m), e1 = expf(v1 - m);
  red[t] = e0 + e1; __syncthreads();
  for (int k = 128; k > 0; k >>= 1){ if (t < k) red[t] += red[t + k]; __syncthreads(); }
  float inv = 1.0f / red[0];
  p[t] = e0 * inv; p[t + 256] = e1 * inv;
}

// ------- ctx = P @ V; write bf16 hi/lo [2048][1024] for split MFMA --------
__global__ __launch_bounds__(256) void ctx_k(const float* __restrict__ P,
                                             const float* __restrict__ qkv,
                                             ushort_t* __restrict__ chi,
                                             ushort_t* __restrict__ clo){
  int bh = blockIdx.y; int b = bh >> 4, h = bh & 15;
  int q0 = blockIdx.x * 64;
  __shared__ float Ps[16][68];
  __shared__ float Vs[16][68];
  int t = threadIdx.x;
  int tx = t & 15, ty = t >> 4;
  int pq = t >> 2, pk = (t & 3) * 4;
  int vk = t >> 4, vd = (t & 15) * 4;
  float acc[4][4] = {};
  for (int kk = 0; kk < TT; kk += 16){
    float4 pv = *(const float4*)&P[((size_t)bh * TT + q0 + pq) * TT + kk + pk];
    Ps[pk + 0][pq] = pv.x; Ps[pk + 1][pq] = pv.y;
    Ps[pk + 2][pq] = pv.z; Ps[pk + 3][pq] = pv.w;
    float4 vv = *(const float4*)&qkv[(size_t)(b * TT + kk + vk) * D3 + 2 * DIM + h * DH + vd];
    Vs[vk][vd + 0] = vv.x; Vs[vk][vd + 1] = vv.y;
    Vs[vk][vd + 2] = vv.z; Vs[vk][vd + 3] = vv.w;
    __syncthreads();
#pragma unroll
    for (int k = 0; k < 16; k++){
      float4 a = *(const float4*)&Ps[k][ty * 4];
      float4 bb = *(const float4*)&Vs[k][tx * 4];
      float aa[4] = {a.x,a.y,a.z,a.w};
      float bv[4] = {bb.x,bb.y,bb.z,bb.w};
#pragma unroll
      for (int i = 0; i < 4; i++)
#pragma unroll
        for (int j = 0; j < 4; j++)
          acc[i][j] += aa[i] * bv[j];
    }
    __syncthreads();
  }
#pragma unroll
  for (int i = 0; i < 4; i++)
#pragma unroll
    for (int j = 0; j < 4; j++){
      float v = acc[i][j];
      size_t idx = (size_t)(b * TT + q0 + ty*4 + i) * DIM + h * DH + tx*4 + j;
      ushort_t hv = f2bf(v);
      chi[idx] = hv;
      clo[idx] = f2bf(v - bf2f(hv));
    }
}

// -------- Gate (exact f32) + top-2 renorm weights -------------------------
__global__ __launch_bounds__(256) void gate_k(const float* __restrict__ ln2f,
                                              const float* __restrict__ wg,
                                              float* __restrict__ we){
  int tok = blockIdx.x * 4 + (threadIdx.x >> 6);
  int lane = threadIdx.x & 63;
  float acc[8] = {};
  for (int d = lane; d < DIM; d += 64){
    float x = ln2f[(size_t)tok * DIM + d];
    float4 w0 = *(const float4*)&wg[d * 8];
    float4 w1v = *(const float4*)&wg[d * 8 + 4];
    float wv[8] = {w0.x,w0.y,w0.z,w0.w,w1v.x,w1v.y,w1v.z,w1v.w};
#pragma unroll
    for (int e = 0; e < 8; e++) acc[e] += x * wv[e];
  }
#pragma unroll
  for (int off = 32; off > 0; off >>= 1){
#pragma unroll
    for (int e = 0; e < 8; e++) acc[e] += __shfl_down(acc[e], off);
  }
  if (lane == 0){
    float m = acc[0];
    for (int e = 1; e < 8; e++) m = fmaxf(m, acc[e]);
    float pr[8], s = 0.f;
    for (int e = 0; e < 8; e++){ pr[e] = expf(acc[e] - m); s += pr[e]; }
    for (int e = 0; e < 8; e++) pr[e] /= s;
    int i0 = 0;
    for (int e = 1; e < 8; e++) if (pr[e] > pr[i0]) i0 = e;
    int i1 = (i0 == 0) ? 1 : 0;
    for (int e = 0; e < 8; e++) if (e != i0 && pr[e] > pr[i1]) i1 = e;
    float sm = pr[i0] + pr[i1];
    for (int e = 0; e < 8; e++)
      we[(size_t)tok * 8 + e] = (e == i0) ? pr[i0] / sm : ((e == i1) ? pr[i1] / sm : 0.f);
  }
}

// -------- Routing: bucket tokens per expert (device-side counts) ----------
__global__ __launch_bounds__(256) void route_k(const float* __restrict__ we,
                                               int* __restrict__ cnt,
                                               int* __restrict__ gidx,
                                               float* __restrict__ gw){
  int tok = blockIdx.x * 256 + threadIdx.x;
#pragma unroll
  for (int e = 0; e < NEXP; e++){
    float w = we[(size_t)tok * NEXP + e];
    if (w > 0.f){
      int p = atomicAdd(&cnt[e], 1);
      gidx[e * N_TOK + p] = tok;
      gw[e * N_TOK + p] = w;
    }
  }
}

// -------- Plan: exclusive scan + dense (expert,row-block) slot table ------
// table[0] = n_slots; table[1+s] = (e<<16)|local_rowblock.  n_slots <= 40.
__global__ void plan_k(const int* __restrict__ cnt, int* __restrict__ off,
                       int* __restrict__ table){
  if (threadIdx.x == 0){
    int s = 0;
    for (int e = 0; e < NEXP; e++){ off[e] = s; s += cnt[e]; }
    int ns = 0;
    for (int e = 0; e < NEXP; e++){
      int nb = (cnt[e] + TBM - 1) / TBM;
      for (int rb = 0; rb < nb; rb++) table[1 + ns++] = (e << 16) | rb;
    }
    table[0] = ns;
  }
}

// -------- Grouped MFMA bf16 expert GEMM: dense slot table -----------------
// blockIdx.y = slot (dense over active row-blocks of all experts).
// EPI 0: K=DIM; blockIdx.x = col (HID/TBN=32). gather rows; gelu->bf16.
// EPI 1: K=HID split 4x1024; blockIdx.x: col = x&7, ks = x>>3.
//        scatter atomicAdd(gw*(acc + [ks==0]bias)).
template<int EPI>
__global__ __launch_bounds__(256) void moe_gemm_g(
    const ushort_t* __restrict__ A,      // EPI0: ln2bf [N_TOK][K]; EPI1: h1e [4096][K]
    const ushort_t* __restrict__ BT_all, // bf16 [E][N][K]
    const float* __restrict__ bias_all,  // [E][N]
    ushort_t* __restrict__ Obf,          // EPI0 out: h1e [4096][Nn]
    float* __restrict__ Of,              // EPI1 out: accb [N_TOK][Nn]
    const int* __restrict__ gidx_all,    // [E][N_TOK]
    const float* __restrict__ gw_all,    // [E][N_TOK]
    const int* __restrict__ cnt,         // [E]
    const int* __restrict__ off,         // [E] exclusive scan
    const int* __restrict__ table,       // plan table
    int Nn)
{
  int ns = table[0];
  int slot = blockIdx.y;
  if (slot >= ns) return;
  int ent = table[1 + slot];
  int e  = ent >> 16;
  int bm = (ent & 0xffff) * TBM;
  int c  = cnt[e];
  int col, ks;
  if (EPI == 0){ col = blockIdx.x; ks = 0; }
  else         { col = blockIdx.x & 7; ks = blockIdx.x >> 3; }
  const int K = (EPI == 0) ? DIM : HID;
  int kbase = ks * 1024;                 // 1024-wide K window, 32 steps
  int bn = col * TBN;
  const int* gidx = gidx_all + e * N_TOK;
  const float* gwp = gw_all + e * N_TOK;
  const ushort_t* BT = BT_all + (size_t)e * Nn * K;
  const float* bias = bias_all + (size_t)e * Nn;
  int obase = off[e];

  __shared__ ushort_t As[TBM * LDK];
  __shared__ ushort_t Bs[TBN * LDK];
  int t = threadIdx.x;
  int lane = t & 63, wave = t >> 6;
  int wm = (wave & 1) * 64, wn = (wave >> 1) * 64;

  int r0 = t >> 2, r1 = r0 + 64;
  int kc = (t & 3) * 8;
  size_t ga0, ga1;
  if (EPI == 0){
    int g0 = bm + r0, g1 = bm + r1;
    ga0 = (size_t)((g0 < c) ? gidx[g0] : gidx[bm]);
    ga1 = (size_t)((g1 < c) ? gidx[g1] : gidx[bm]);
  } else {
    int mx = 2 * N_TOK - 1;
    int g0 = obase + bm + r0; if (g0 > mx) g0 = mx;
    int g1 = obase + bm + r1; if (g1 > mx) g1 = mx;
    ga0 = (size_t)g0; ga1 = (size_t)g1;
  }
  const ushort_t* a0p = A + ga0 * K + kbase + kc;
  const ushort_t* a1p = A + ga1 * K + kbase + kc;
  const ushort_t* b0p = BT + (size_t)(bn + r0) * K + kbase + kc;
  const ushort_t* b1p = BT + (size_t)(bn + r1) * K + kbase + kc;

  f32x4 acc[4][4] = {};
  int fm = lane & 15, fk = (lane >> 4) * 8;

  // 2-deep register prefetch: slot A = tile it, slot B = tile it+1
  uint4 Aa0 = *(const uint4*)(a0p);
  uint4 Aa1 = *(const uint4*)(a1p);
  uint4 Ba0 = *(const uint4*)(b0p);
  uint4 Ba1 = *(const uint4*)(b1p);
  uint4 Ab0 = *(const uint4*)(a0p + TBK);
  uint4 Ab1 = *(const uint4*)(a1p + TBK);
  uint4 Bb0 = *(const uint4*)(b0p + TBK);
  uint4 Bb1 = *(const uint4*)(b1p + TBK);

  const int KSTEPS = 32;
  for (int it = 0; it < KSTEPS; it += 2){
    // ---- even tile (slot A) ----
    *(uint4*)&As[r0 * LDK + kc] = Aa0;
    *(uint4*)&As[r1 * LDK + kc] = Aa1;
    *(uint4*)&Bs[r0 * LDK + kc] = Ba0;
    *(uint4*)&Bs[r1 * LDK + kc] = Ba1;
    __syncthreads();
    if (it + 2 < KSTEPS){
      int kn = (it + 2) * TBK;
      Aa0 = *(const uint4*)(a0p + kn);
      Aa1 = *(const uint4*)(a1p + kn);
      Ba0 = *(const uint4*)(b0p + kn);
      Ba1 = *(const uint4*)(b1p + kn);
    }
    {
      short8 af[4], bfr[4];
#pragma unroll
      for (int mi = 0; mi < 4; mi++)
        af[mi] = *(const short8*)&As[(wm + mi*16 + fm) * LDK + fk];
#pragma unroll
      for (int nj = 0; nj < 4; nj++)
        bfr[nj] = *(const short8*)&Bs[(wn + nj*16 + fm) * LDK + fk];
#pragma unroll
      for (int mi = 0; mi < 4; mi++)
#pragma unroll
        for (int nj = 0; nj < 4; nj++)
          acc[mi][nj] = __builtin_amdgcn_mfma_f32_16x16x32_bf16(af[mi], bfr[nj], acc[mi][nj], 0, 0, 0);
    }
    __syncthreads();
    // ---- odd tile (slot B) ----
    *(uint4*)&As[r0 * LDK + kc] = Ab0;
    *(uint4*)&As[r1 * LDK + kc] = Ab1;
    *(uint4*)&Bs[r0 * LDK + kc] = Bb0;
    *(uint4*)&Bs[r1 * LDK + kc] = Bb1;
    __syncthreads();
    if (it + 3 < KSTEPS){
      int kn = (it + 3) * TBK;
      Ab0 = *(const uint4*)(a0p + kn);
      Ab1 = *(const uint4*)(a1p + kn);
      Bb0 = *(const uint4*)(b0p + kn);
      Bb1 = *(const uint4*)(b1p + kn);
    }
    {
      short8 af[4], bfr[4];
#pragma unroll
      for (int mi = 0; mi < 4; mi++)
        af[mi] = *(const short8*)&As[(wm + mi*16 + fm) * LDK + fk];
#pragma unroll
      for (int nj = 0; nj < 4; nj++)
        bfr[nj] = *(const short8*)&Bs[(wn + nj*16 + fm) * LDK + fk];
#pragma unroll
      for (int mi = 0; mi < 4; mi++)
#pragma unroll
        for (int nj = 0; nj < 4; nj++)
          acc[mi][nj] = __builtin_amdgcn_mfma_f32_16x16x32_bf16(af[mi], bfr[nj], acc[mi][nj], 0, 0, 0);
    }
    __syncthreads();
  }

  // epilogue: C/D layout col=lane&15, row=(lane>>4)*4+reg  [m89-verified]
#pragma unroll
  for (int mi = 0; mi < 4; mi++){
    int rowbase = bm + wm + mi*16 + (lane >> 4) * 4;
#pragma unroll
    for (int nj = 0; nj < 4; nj++){
      int n = bn + wn + nj*16 + (lane & 15);
      f32x4 v = acc[mi][nj];
#pragma unroll
      for (int rg = 0; rg < 4; rg++){
        int r = rowbase + rg;
        if (r < c){
          if (EPI == 0){
            float val = v[rg] + bias[n];
            Obf[(size_t)(obase + r) * Nn + n] = f2bf(gelu_f(val));
          } else {
            float val = v[rg];
            if (ks == 0) val += bias[n];
            int tok = gidx[r];
            atomicAdd(&Of[(size_t)tok * Nn + n], gwp[r] * val);
          }
        }
      }
    }
  }
}

// ---------------- Final: out = h + moe_acc (f32) --------------------------
__global__ __launch_bounds__(256) void final_k(const float* __restrict__ h,
                                               const float* __restrict__ acc,
                                               float* __restrict__ out){
  size_t i = (size_t)blockIdx.x * 256 + threadIdx.x;
  out[i] = h[i] + acc[i];
}

extern "C" void kernel_launch(void* const* d_in, const int* in_sizes, int n_in,
                              void* d_out, int out_size, void* d_ws, size_t ws_size,
                              hipStream_t stream){
  const float* x     = (const float*)d_in[0];
  const float* ln1w  = (const float*)d_in[1];
  const float* ln1b  = (const float*)d_in[2];
  const float* ln2w  = (const float*)d_in[3];
  const float* ln2b  = (const float*)d_in[4];
  const float* wqkv  = (const float*)d_in[5];
  const float* bqkv  = (const float*)d_in[6];
  const float* wo    = (const float*)d_in[7];
  const float* bo    = (const float*)d_in[8];
  const float* wgate = (const float*)d_in[9];
  const float* w1    = (const float*)d_in[10];
  const float* b1    = (const float*)d_in[11];
  const float* w2    = (const float*)d_in[12];
  const float* b2    = (const float*)d_in[13];

  // Workspace map (121 MB peak, lifetimes disjoint — see round-2 notes):
  char* ws = (char*)d_ws;
  const size_t MB = 1024 * 1024;
  float*    hbuf  = (float*)(ws + 0 * MB);
  ushort_t* ln1hi = (ushort_t*)(ws + 0 * MB);
  ushort_t* ln1lo = (ushort_t*)(ws + 4 * MB);
  float*    accb  = (float*)(ws + 8 * MB);
  ushort_t* wqkvThi = (ushort_t*)(ws + 8 * MB);             // 6 MB
  ushort_t* wqkvTlo = (ushort_t*)(ws + 14 * MB);            // 6 MB
  ushort_t* ln2bf = (ushort_t*)(ws + 16 * MB);              // 4 MB
  ushort_t* h1e   = (ushort_t*)(ws + 20 * MB);              // 32 MB
  float*    qkv   = (float*)(ws + 20 * MB);                 // 24 MB
  float*    ln2f  = (float*)(ws + 24 * MB);                 // 8 MB
  ushort_t* ctxhi = (ushort_t*)(ws + 44 * MB);
  ushort_t* ctxlo = (ushort_t*)(ws + 48 * MB);
  ushort_t* woThi = (ushort_t*)(ws + 52 * MB);              // 2 MB
  ushort_t* woTlo = (ushort_t*)(ws + 54 * MB);              // 2 MB
  float*    sc    = (float*)(ws + 56 * MB);                 // 64 MB
  ushort_t* wTe   = (ushort_t*)(ws + 56 * MB);              // 64 MB
  float*    webuf = (float*)(ws + 120 * MB);                // 64 KB
  int*      cnt   = (int*)  (ws + 120 * MB + 256 * 1024);   // 32 B
  int*      off   = (int*)  (ws + 120 * MB + 260 * 1024);   // 32 B
  int*      table = (int*)  (ws + 120 * MB + 264 * 1024);   // 256 B
  int*      bidx  = (int*)  (ws + 120 * MB + 320 * 1024);   // 64 KB
  float*    bw    = (float*)(ws + 120 * MB + 448 * 1024);   // 64 KB

  // ---- attention path: split-bf16 MFMA GEMMs (near-f32 accuracy) ----
  ln_k<2><<<N_TOK, 256, 0, stream>>>(x, ln1w, ln1b, nullptr, ln1hi, ln1lo);
  convT2<<<dim3(D3 / 64, DIM / 64), 256, 0, stream>>>(wqkv, wqkvThi, wqkvTlo, DIM, D3);
  gemm_split<0><<<(N_TOK / TBM) * (D3 / TBN), 256, 0, stream>>>(
      ln1hi, ln1lo, wqkvThi, wqkvTlo, bqkv, qkv, nullptr, D3, DIM, N_TOK / TBM);
  scores_k<<<dim3(8, 8, 64), 256, 0, stream>>>(qkv, sc);
  softmax_k<<<64 * TT, 256, 0, stream>>>(sc);
  ctx_k<<<dim3(8, 64), 256, 0, stream>>>(sc, qkv, ctxhi, ctxlo);
  // sc dead -> convert ALL expert w1 into wTe (one launch)
  convT_g<<<dim3(HID / 64, DIM / 64, NEXP), 256, 0, stream>>>(w1, wTe, DIM, HID);
  convT2<<<dim3(DIM / 64, DIM / 64), 256, 0, stream>>>(wo, woThi, woTlo, DIM, DIM);
  gemm_split<1><<<(N_TOK / TBM) * (DIM / TBN), 256, 0, stream>>>(
      ctxhi, ctxlo, woThi, woTlo, bo, hbuf, x, DIM, DIM, N_TOK / TBM);
  ln_k<1><<<N_TOK, 256, 0, stream>>>(hbuf, ln2w, ln2b, ln2f, ln2bf, nullptr);
  gate_k<<<N_TOK / 4, 256, 0, stream>>>(ln2f, wgate, webuf);

  // ---- routed MoE: dense slot-table grouped GEMMs ----
  hipMemsetAsync(cnt, 0, 32, stream);
  hipMemsetAsync(accb, 0, (size_t)N_TOK * DIM * 4, stream);
  route_k<<<N_TOK / 256, 256, 0, stream>>>(webuf, cnt, bidx, bw);
  plan_k<<<1, 64, 0, stream>>>(cnt, off, table);
  // GEMM1: 32 cols x <=40 dense row-slots
  moe_gemm_g<0><<<dim3(HID / TBN, 40), 256, 0, stream>>>(
      ln2bf, wTe, b1, h1e, nullptr, bidx, bw, cnt, off, table, HID);
  convT_g<<<dim3(DIM / 64, HID / 64, NEXP), 256, 0, stream>>>(w2, wTe, HID, DIM);
  // GEMM2: (8 cols x 4 ksplit) x <=40 dense row-slots
  moe_gemm_g<1><<<dim3(32, 40), 256, 0, stream>>>(
      h1e, wTe, b2, nullptr, accb, bidx, bw, cnt, off, table, DIM);
  final_k<<<(N_TOK * DIM) / 256, 256, 0, stream>>>(hbuf, accb, (float*)d_out);
}

// Round 5
// 810.714 us; speedup vs baseline: 1.0884x; 1.0153x over previous
//
#include <hip/hip_runtime.h>
#include <math.h>

typedef unsigned short ushort_t;
using short8 = __attribute__((ext_vector_type(8))) short;
using f32x4  = __attribute__((ext_vector_type(4))) float;

#define N_TOK 2048
#define DIM   1024
#define D3    3072
#define NHEAD 16
#define DH    64
#define TT    512
#define HID   4096
#define NEXP  8

__device__ __forceinline__ float bf2f(ushort_t u){
  union { unsigned int i; float f; } x; x.i = ((unsigned int)u) << 16; return x.f;
}
__device__ __forceinline__ ushort_t f2bf(float f){
  union { unsigned int i; float f; } x; x.f = f;
  unsigned int r = x.i + 0x7fffu + ((x.i >> 16) & 1u);
  return (ushort_t)(r >> 16);
}
__device__ __forceinline__ float gelu_f(float x){
  const float c = 0.7978845608028654f; // sqrt(2/pi)
  float t = tanhf(c * (x + 0.044715f * x * x * x));
  return 0.5f * x * (1.0f + t);
}
// async global->LDS DMA, 16B per lane; LDS dest = wave-uniform base + lane*16
__device__ __forceinline__ void gload16(const ushort_t* g, ushort_t* l){
  __builtin_amdgcn_global_load_lds((const unsigned int*)g, (unsigned int*)l, 16, 0, 0);
}

// ------- LayerNorm ---------------------------------------------------------
template<int MODE>
__global__ __launch_bounds__(256) void ln_k(const float* __restrict__ xin,
                                            const float* __restrict__ w,
                                            const float* __restrict__ b,
                                            float* __restrict__ out,
                                            ushort_t* __restrict__ outhi,
                                            ushort_t* __restrict__ outlo){
  int tok = blockIdx.x;
  int t = threadIdx.x;
  float vals[4]; float s = 0.f, ss = 0.f;
#pragma unroll
  for (int i = 0; i < 4; i++){
    int d = t + i * 256;
    float v = xin[(size_t)tok * DIM + d];
    vals[i] = v; s += v; ss += v * v;
  }
  __shared__ float rs[256], rq[256];
  rs[t] = s; rq[t] = ss; __syncthreads();
  for (int k = 128; k > 0; k >>= 1){
    if (t < k){ rs[t] += rs[t + k]; rq[t] += rq[t + k]; }
    __syncthreads();
  }
  float mu  = rs[0] * (1.0f / DIM);
  float var = rq[0] * (1.0f / DIM) - mu * mu;
  float inv = rsqrtf(var + 1e-5f);
#pragma unroll
  for (int i = 0; i < 4; i++){
    int d = t + i * 256;
    float r = (vals[i] - mu) * inv * w[d] + b[d];
    size_t idx = (size_t)tok * DIM + d;
    if (MODE == 1){
      out[idx] = r;
      outhi[idx] = f2bf(r);
    } else {
      ushort_t hv = f2bf(r);
      outhi[idx] = hv;
      outlo[idx] = f2bf(r - bf2f(hv));
    }
  }
}

// -------- Transpose-convert split: src f32 [R][C] -> hi/lo bf16 [C][R] ----
__global__ __launch_bounds__(256) void convT2(const float* __restrict__ src,
                                              ushort_t* __restrict__ dhi,
                                              ushort_t* __restrict__ dlo,
                                              int R, int C){
  __shared__ float tile[64][65];
  int r0 = blockIdx.y * 64, c0 = blockIdx.x * 64;
  int t = threadIdx.x;
  int tc = t & 15, tr = t >> 4;
#pragma unroll
  for (int i = 0; i < 4; i++){
    int r = tr + i * 16;
    float4 v = *(const float4*)&src[(size_t)(r0 + r) * C + c0 + tc * 4];
    tile[r][tc*4 + 0] = v.x; tile[r][tc*4 + 1] = v.y;
    tile[r][tc*4 + 2] = v.z; tile[r][tc*4 + 3] = v.w;
  }
  __syncthreads();
#pragma unroll
  for (int i = 0; i < 4; i++){
    int c = tr + i * 16;
    float v0 = tile[tc*4 + 0][c];
    float v1 = tile[tc*4 + 1][c];
    float v2 = tile[tc*4 + 2][c];
    float v3 = tile[tc*4 + 3][c];
    ushort4 oh, ol;
    oh.x = f2bf(v0); ol.x = f2bf(v0 - bf2f(oh.x));
    oh.y = f2bf(v1); ol.y = f2bf(v1 - bf2f(oh.y));
    oh.z = f2bf(v2); ol.z = f2bf(v2 - bf2f(oh.z));
    oh.w = f2bf(v3); ol.w = f2bf(v3 - bf2f(oh.w));
    size_t o = (size_t)(c0 + c) * R + r0 + tc * 4;
    *(ushort4*)&dhi[o] = oh;
    *(ushort4*)&dlo[o] = ol;
  }
}

// -------- Grouped transpose-convert: per-expert f32 [R][C] -> bf16 [C][R] -
__global__ __launch_bounds__(256) void convT_g(const float* __restrict__ src0,
                                               ushort_t* __restrict__ dst0,
                                               int R, int C){
  size_t eo = (size_t)blockIdx.z * R * C;
  const float* src = src0 + eo;
  ushort_t* dst = dst0 + eo;
  __shared__ float tile[64][65];
  int r0 = blockIdx.y * 64, c0 = blockIdx.x * 64;
  int t = threadIdx.x;
  int tc = t & 15, tr = t >> 4;
#pragma unroll
  for (int i = 0; i < 4; i++){
    int r = tr + i * 16;
    float4 v = *(const float4*)&src[(size_t)(r0 + r) * C + c0 + tc * 4];
    tile[r][tc*4 + 0] = v.x; tile[r][tc*4 + 1] = v.y;
    tile[r][tc*4 + 2] = v.z; tile[r][tc*4 + 3] = v.w;
  }
  __syncthreads();
#pragma unroll
  for (int i = 0; i < 4; i++){
    int c = tr + i * 16;
    ushort4 o;
    o.x = f2bf(tile[tc*4 + 0][c]);
    o.y = f2bf(tile[tc*4 + 1][c]);
    o.z = f2bf(tile[tc*4 + 2][c]);
    o.w = f2bf(tile[tc*4 + 3][c]);
    *(ushort4*)&dst[(size_t)(c0 + c) * R + r0 + tc * 4] = o;
  }
}

// -------- Split-bf16 MFMA GEMM (m97-style global_load_lds staging) --------
// LDS tiles are LINEAR [128][32] bf16 (64B rows) — required by global_load_lds
// (wave-uniform base + lane*16B). Staging: wave w owns rows [w*32,w*32+32);
// instr i covers 16 rows; lane l -> row l>>2, k-slot (l&3)*8.
#define TBM 128
#define TBN 128
#define TBK 32
#define LDB 32   // linear LDS row stride (bf16 elems)

template<int EPI>
__global__ __launch_bounds__(256) void gemm_split(
    const ushort_t* __restrict__ Ahi, const ushort_t* __restrict__ Alo,
    const ushort_t* __restrict__ Bhi, const ushort_t* __restrict__ Blo,
    const float* __restrict__ bias,
    float* __restrict__ C, const float* __restrict__ Res,
    int Nn, int K, int mblocks)
{
  int q = gridDim.x >> 3;
  int L = (blockIdx.x & 7) * q + (blockIdx.x >> 3);
  int bm = (L % mblocks) * TBM;
  int bn = (L / mblocks) * TBN;
  __shared__ ushort_t Ah[TBM * LDB];
  __shared__ ushort_t Al[TBM * LDB];
  __shared__ ushort_t Bh[TBN * LDB];
  __shared__ ushort_t Bl[TBN * LDB];
  int t = threadIdx.x;
  int lane = t & 63, wave = t >> 6;
  int wm = (wave & 1) * 64, wn = (wave >> 1) * 64;

  // staging coordinates (fixed per lane across K-steps)
  int sr0 = wave * 32 + (lane >> 2);
  int sr1 = sr0 + 16;
  int sc  = (lane & 3) * 8;
  const ushort_t* ah0 = Ahi + (size_t)(bm + sr0) * K + sc;
  const ushort_t* ah1 = Ahi + (size_t)(bm + sr1) * K + sc;
  const ushort_t* al0 = Alo + (size_t)(bm + sr0) * K + sc;
  const ushort_t* al1 = Alo + (size_t)(bm + sr1) * K + sc;
  const ushort_t* bh0 = Bhi + (size_t)(bn + sr0) * K + sc;
  const ushort_t* bh1 = Bhi + (size_t)(bn + sr1) * K + sc;
  const ushort_t* bl0 = Blo + (size_t)(bn + sr0) * K + sc;
  const ushort_t* bl1 = Blo + (size_t)(bn + sr1) * K + sc;
  ushort_t* lAh0 = Ah + (wave * 32) * LDB;
  ushort_t* lAh1 = Ah + (wave * 32 + 16) * LDB;
  ushort_t* lAl0 = Al + (wave * 32) * LDB;
  ushort_t* lAl1 = Al + (wave * 32 + 16) * LDB;
  ushort_t* lBh0 = Bh + (wave * 32) * LDB;
  ushort_t* lBh1 = Bh + (wave * 32 + 16) * LDB;
  ushort_t* lBl0 = Bl + (wave * 32) * LDB;
  ushort_t* lBl1 = Bl + (wave * 32 + 16) * LDB;

  f32x4 acc[4][4] = {};
  int fm = lane & 15, fk = (lane >> 4) * 8;

  for (int k0 = 0; k0 < K; k0 += TBK){
    gload16(ah0 + k0, lAh0); gload16(ah1 + k0, lAh1);
    gload16(al0 + k0, lAl0); gload16(al1 + k0, lAl1);
    gload16(bh0 + k0, lBh0); gload16(bh1 + k0, lBh1);
    gload16(bl0 + k0, lBl0); gload16(bl1 + k0, lBl1);
    __syncthreads();
    short8 afh[4], afl[4], bfh[4], bfl[4];
#pragma unroll
    for (int mi = 0; mi < 4; mi++){
      afh[mi] = *(const short8*)&Ah[(wm + mi*16 + fm) * LDB + fk];
      afl[mi] = *(const short8*)&Al[(wm + mi*16 + fm) * LDB + fk];
    }
#pragma unroll
    for (int nj = 0; nj < 4; nj++){
      bfh[nj] = *(const short8*)&Bh[(wn + nj*16 + fm) * LDB + fk];
      bfl[nj] = *(const short8*)&Bl[(wn + nj*16 + fm) * LDB + fk];
    }
#pragma unroll
    for (int mi = 0; mi < 4; mi++)
#pragma unroll
      for (int nj = 0; nj < 4; nj++){
        acc[mi][nj] = __builtin_amdgcn_mfma_f32_16x16x32_bf16(afh[mi], bfh[nj], acc[mi][nj], 0, 0, 0);
        acc[mi][nj] = __builtin_amdgcn_mfma_f32_16x16x32_bf16(afh[mi], bfl[nj], acc[mi][nj], 0, 0, 0);
        acc[mi][nj] = __builtin_amdgcn_mfma_f32_16x16x32_bf16(afl[mi], bfh[nj], acc[mi][nj], 0, 0, 0);
      }
    __syncthreads();
  }

#pragma unroll
  for (int mi = 0; mi < 4; mi++){
    int rowbase = bm + wm + mi*16 + (lane >> 4) * 4;
#pragma unroll
    for (int nj = 0; nj < 4; nj++){
      int n = bn + wn + nj*16 + (lane & 15);
      f32x4 v = acc[mi][nj];
#pragma unroll
      for (int rg = 0; rg < 4; rg++){
        size_t idx = (size_t)(rowbase + rg) * Nn + n;
        float val = v[rg] + bias[n];
        if (EPI == 1) val += Res[idx];
        C[idx] = val;
      }
    }
  }
}

// ---------------- Attention scores: S[bh,q,k] = (Q·K)/8 -------------------
__global__ __launch_bounds__(256) void scores_k(const float* __restrict__ qkv,
                                                float* __restrict__ S){
  int bh = blockIdx.z; int b = bh >> 4, h = bh & 15;
  int q0 = blockIdx.y * 64, k0 = blockIdx.x * 64;
  __shared__ float Qs[64][68];
  __shared__ float Ks[64][68];
  int t = threadIdx.x;
  int r = t >> 2, dp = (t & 3) * 16;
  {
    const float* qp = qkv + (size_t)(b * TT + q0 + r) * D3 + h * DH + dp;
    const float* kp = qkv + (size_t)(b * TT + k0 + r) * D3 + DIM + h * DH + dp;
#pragma unroll
    for (int c = 0; c < 4; c++){
      float4 qv = *(const float4*)(qp + c * 4);
      float4 kv = *(const float4*)(kp + c * 4);
      Qs[dp + c*4 + 0][r] = qv.x; Qs[dp + c*4 + 1][r] = qv.y;
      Qs[dp + c*4 + 2][r] = qv.z; Qs[dp + c*4 + 3][r] = qv.w;
      Ks[dp + c*4 + 0][r] = kv.x; Ks[dp + c*4 + 1][r] = kv.y;
      Ks[dp + c*4 + 2][r] = kv.z; Ks[dp + c*4 + 3][r] = kv.w;
    }
  }
  __syncthreads();
  int tx = t & 15, ty = t >> 4;
  float acc[4][4] = {};
#pragma unroll 8
  for (int d = 0; d < 64; d++){
    float4 qv = *(const float4*)&Qs[d][ty * 4];
    float4 kv = *(const float4*)&Ks[d][tx * 4];
    float qa[4] = {qv.x,qv.y,qv.z,qv.w};
    float ka[4] = {kv.x,kv.y,kv.z,kv.w};
#pragma unroll
    for (int i = 0; i < 4; i++)
#pragma unroll
      for (int j = 0; j < 4; j++)
        acc[i][j] += qa[i] * ka[j];
  }
#pragma unroll
  for (int i = 0; i < 4; i++)
#pragma unroll
    for (int j = 0; j < 4; j++)
      S[((size_t)bh * TT + q0 + ty*4 + i) * TT + k0 + tx*4 + j] = acc[i][j] * 0.125f;
}

// ---------------- Softmax over rows of 512 --------------------------------
__global__ __launch_bounds__(256) void softmax_k(float* __restrict__ S){
  size_t row = blockIdx.x;
  float* p = S + row * TT;
  int t = threadIdx.x;
  float v0 = p[t], v1 = p[t + 256];
  __shared__ float red[256];
  red[t] = fmaxf(v0, v1); __syncthreads();
  for (int k = 128; k > 0; k >>= 1){ if (t < k) red[t] = fmaxf(red[t], red[t + k]); __syncthreads(); }
  float m = red[0]; __syncthreads();
  float e0 = expf(v0 - m), e1 = expf(v1 - m);
  red[t] = e0 + e1; __syncthreads();
  for (int k = 128; k > 0; k >>= 1){ if (t < k) red[t] += red[t + k]; __syncthreads(); }
  float inv = 1.0f / red[0];
  p[t] = e0 * inv; p[t + 256] = e1 * inv;
}

// ------- ctx = P @ V; write bf16 hi/lo [2048][1024] for split MFMA --------
__global__ __launch_bounds__(256) void ctx_k(const float* __restrict__ P,
                                             const float* __restrict__ qkv,
                                             ushort_t* __restrict__ chi,
                                             ushort_t* __restrict__ clo){
  int bh = blockIdx.y; int b = bh >> 4, h = bh & 15;
  int q0 = blockIdx.x * 64;
  __shared__ float Ps[16][68];
  __shared__ float Vs[16][68];
  int t = threadIdx.x;
  int tx = t & 15, ty = t >> 4;
  int pq = t >> 2, pk = (t & 3) * 4;
  int vk = t >> 4, vd = (t & 15) * 4;
  float acc[4][4] = {};
  for (int kk = 0; kk < TT; kk += 16){
    float4 pv = *(const float4*)&P[((size_t)bh * TT + q0 + pq) * TT + kk + pk];
    Ps[pk + 0][pq] = pv.x; Ps[pk + 1][pq] = pv.y;
    Ps[pk + 2][pq] = pv.z; Ps[pk + 3][pq] = pv.w;
    float4 vv = *(const float4*)&qkv[(size_t)(b * TT + kk + vk) * D3 + 2 * DIM + h * DH + vd];
    Vs[vk][vd + 0] = vv.x; Vs[vk][vd + 1] = vv.y;
    Vs[vk][vd + 2] = vv.z; Vs[vk][vd + 3] = vv.w;
    __syncthreads();
#pragma unroll
    for (int k = 0; k < 16; k++){
      float4 a = *(const float4*)&Ps[k][ty * 4];
      float4 bb = *(const float4*)&Vs[k][tx * 4];
      float aa[4] = {a.x,a.y,a.z,a.w};
      float bv[4] = {bb.x,bb.y,bb.z,bb.w};
#pragma unroll
      for (int i = 0; i < 4; i++)
#pragma unroll
        for (int j = 0; j < 4; j++)
          acc[i][j] += aa[i] * bv[j];
    }
    __syncthreads();
  }
#pragma unroll
  for (int i = 0; i < 4; i++)
#pragma unroll
    for (int j = 0; j < 4; j++){
      float v = acc[i][j];
      size_t idx = (size_t)(b * TT + q0 + ty*4 + i) * DIM + h * DH + tx*4 + j;
      ushort_t hv = f2bf(v);
      chi[idx] = hv;
      clo[idx] = f2bf(v - bf2f(hv));
    }
}

// -------- Gate (exact f32) + top-2 renorm weights -------------------------
__global__ __launch_bounds__(256) void gate_k(const float* __restrict__ ln2f,
                                              const float* __restrict__ wg,
                                              float* __restrict__ we){
  int tok = blockIdx.x * 4 + (threadIdx.x >> 6);
  int lane = threadIdx.x & 63;
  float acc[8] = {};
  for (int d = lane; d < DIM; d += 64){
    float x = ln2f[(size_t)tok * DIM + d];
    float4 w0 = *(const float4*)&wg[d * 8];
    float4 w1v = *(const float4*)&wg[d * 8 + 4];
    float wv[8] = {w0.x,w0.y,w0.z,w0.w,w1v.x,w1v.y,w1v.z,w1v.w};
#pragma unroll
    for (int e = 0; e < 8; e++) acc[e] += x * wv[e];
  }
#pragma unroll
  for (int off = 32; off > 0; off >>= 1){
#pragma unroll
    for (int e = 0; e < 8; e++) acc[e] += __shfl_down(acc[e], off);
  }
  if (lane == 0){
    float m = acc[0];
    for (int e = 1; e < 8; e++) m = fmaxf(m, acc[e]);
    float pr[8], s = 0.f;
    for (int e = 0; e < 8; e++){ pr[e] = expf(acc[e] - m); s += pr[e]; }
    for (int e = 0; e < 8; e++) pr[e] /= s;
    int i0 = 0;
    for (int e = 1; e < 8; e++) if (pr[e] > pr[i0]) i0 = e;
    int i1 = (i0 == 0) ? 1 : 0;
    for (int e = 0; e < 8; e++) if (e != i0 && pr[e] > pr[i1]) i1 = e;
    float sm = pr[i0] + pr[i1];
    for (int e = 0; e < 8; e++)
      we[(size_t)tok * 8 + e] = (e == i0) ? pr[i0] / sm : ((e == i1) ? pr[i1] / sm : 0.f);
  }
}

// -------- Routing: bucket tokens per expert (device-side counts) ----------
__global__ __launch_bounds__(256) void route_k(const float* __restrict__ we,
                                               int* __restrict__ cnt,
                                               int* __restrict__ gidx,
                                               float* __restrict__ gw){
  int tok = blockIdx.x * 256 + threadIdx.x;
#pragma unroll
  for (int e = 0; e < NEXP; e++){
    float w = we[(size_t)tok * NEXP + e];
    if (w > 0.f){
      int p = atomicAdd(&cnt[e], 1);
      gidx[e * N_TOK + p] = tok;
      gw[e * N_TOK + p] = w;
    }
  }
}

// -------- Plan: exclusive scan + dense (expert,row-block) slot table ------
__global__ void plan_k(const int* __restrict__ cnt, int* __restrict__ off,
                       int* __restrict__ table){
  if (threadIdx.x == 0){
    int s = 0;
    for (int e = 0; e < NEXP; e++){ off[e] = s; s += cnt[e]; }
    int ns = 0;
    for (int e = 0; e < NEXP; e++){
      int nb = (cnt[e] + TBM - 1) / TBM;
      for (int rb = 0; rb < nb; rb++) table[1 + ns++] = (e << 16) | rb;
    }
    table[0] = ns;
  }
}

// -------- Grouped MFMA bf16 expert GEMM: dense slot table, gload_lds ------
// blockIdx.y = slot; EPI 0: col = blockIdx.x (32). EPI 1: col = x&7, ks = x>>3.
template<int EPI>
__global__ __launch_bounds__(256) void moe_gemm_g(
    const ushort_t* __restrict__ A,      // EPI0: ln2bf [N_TOK][K]; EPI1: h1e [4096][K]
    const ushort_t* __restrict__ BT_all, // bf16 [E][N][K]
    const float* __restrict__ bias_all,  // [E][N]
    ushort_t* __restrict__ Obf,          // EPI0 out: h1e [4096][Nn]
    float* __restrict__ Of,              // EPI1 out: accb [N_TOK][Nn]
    const int* __restrict__ gidx_all,    // [E][N_TOK]
    const float* __restrict__ gw_all,    // [E][N_TOK]
    const int* __restrict__ cnt,         // [E]
    const int* __restrict__ off,         // [E] exclusive scan
    const int* __restrict__ table,       // plan table
    int Nn)
{
  int ns = table[0];
  int slot = blockIdx.y;
  if (slot >= ns) return;
  int ent = table[1 + slot];
  int e  = ent >> 16;
  int bm = (ent & 0xffff) * TBM;
  int c  = cnt[e];
  int col, ks;
  if (EPI == 0){ col = blockIdx.x; ks = 0; }
  else         { col = blockIdx.x & 7; ks = blockIdx.x >> 3; }
  const int K = (EPI == 0) ? DIM : HID;
  int kbase = ks * 1024;                 // 1024-wide K window, 32 steps
  int bn = col * TBN;
  const int* gidx = gidx_all + e * N_TOK;
  const float* gwp = gw_all + e * N_TOK;
  const ushort_t* BT = BT_all + (size_t)e * Nn * K;
  const float* bias = bias_all + (size_t)e * Nn;
  int obase = off[e];

  __shared__ ushort_t As[TBM * LDB];
  __shared__ ushort_t Bs[TBN * LDB];
  int t = threadIdx.x;
  int lane = t & 63, wave = t >> 6;
  int wm = (wave & 1) * 64, wn = (wave >> 1) * 64;

  // staging coordinates (fixed per lane)
  int sr0 = wave * 32 + (lane >> 2);
  int sr1 = sr0 + 16;
  int sc  = (lane & 3) * 8;
  size_t ga0, ga1;
  if (EPI == 0){
    int g0 = bm + sr0, g1 = bm + sr1;
    ga0 = (size_t)((g0 < c) ? gidx[g0] : gidx[bm]);
    ga1 = (size_t)((g1 < c) ? gidx[g1] : gidx[bm]);
  } else {
    int mx = 2 * N_TOK - 1;
    int g0 = obase + bm + sr0; if (g0 > mx) g0 = mx;
    int g1 = obase + bm + sr1; if (g1 > mx) g1 = mx;
    ga0 = (size_t)g0; ga1 = (size_t)g1;
  }
  const ushort_t* a0p = A + ga0 * K + kbase + sc;
  const ushort_t* a1p = A + ga1 * K + kbase + sc;
  const ushort_t* b0p = BT + (size_t)(bn + sr0) * K + kbase + sc;
  const ushort_t* b1p = BT + (size_t)(bn + sr1) * K + kbase + sc;
  ushort_t* lA0 = As + (wave * 32) * LDB;
  ushort_t* lA1 = As + (wave * 32 + 16) * LDB;
  ushort_t* lB0 = Bs + (wave * 32) * LDB;
  ushort_t* lB1 = Bs + (wave * 32 + 16) * LDB;

  f32x4 acc[4][4] = {};
  int fm = lane & 15, fk = (lane >> 4) * 8;

  for (int k0 = 0; k0 < 1024; k0 += TBK){
    gload16(a0p + k0, lA0);
    gload16(a1p + k0, lA1);
    gload16(b0p + k0, lB0);
    gload16(b1p + k0, lB1);
    __syncthreads();
    short8 af[4], bfr[4];
#pragma unroll
    for (int mi = 0; mi < 4; mi++)
      af[mi] = *(const short8*)&As[(wm + mi*16 + fm) * LDB + fk];
#pragma unroll
    for (int nj = 0; nj < 4; nj++)
      bfr[nj] = *(const short8*)&Bs[(wn + nj*16 + fm) * LDB + fk];
#pragma unroll
    for (int mi = 0; mi < 4; mi++)
#pragma unroll
      for (int nj = 0; nj < 4; nj++)
        acc[mi][nj] = __builtin_amdgcn_mfma_f32_16x16x32_bf16(af[mi], bfr[nj], acc[mi][nj], 0, 0, 0);
    __syncthreads();
  }

  // epilogue: C/D layout col=lane&15, row=(lane>>4)*4+reg  [m89-verified]
#pragma unroll
  for (int mi = 0; mi < 4; mi++){
    int rowbase = bm + wm + mi*16 + (lane >> 4) * 4;
#pragma unroll
    for (int nj = 0; nj < 4; nj++){
      int n = bn + wn + nj*16 + (lane & 15);
      f32x4 v = acc[mi][nj];
#pragma unroll
      for (int rg = 0; rg < 4; rg++){
        int r = rowbase + rg;
        if (r < c){
          if (EPI == 0){
            float val = v[rg] + bias[n];
            Obf[(size_t)(obase + r) * Nn + n] = f2bf(gelu_f(val));
          } else {
            float val = v[rg];
            if (ks == 0) val += bias[n];
            int tok = gidx[r];
            atomicAdd(&Of[(size_t)tok * Nn + n], gwp[r] * val);
          }
        }
      }
    }
  }
}

// ---------------- Final: out = h + moe_acc (f32) --------------------------
__global__ __launch_bounds__(256) void final_k(const float* __restrict__ h,
                                               const float* __restrict__ acc,
                                               float* __restrict__ out){
  size_t i = (size_t)blockIdx.x * 256 + threadIdx.x;
  out[i] = h[i] + acc[i];
}

extern "C" void kernel_launch(void* const* d_in, const int* in_sizes, int n_in,
                              void* d_out, int out_size, void* d_ws, size_t ws_size,
                              hipStream_t stream){
  const float* x     = (const float*)d_in[0];
  const float* ln1w  = (const float*)d_in[1];
  const float* ln1b  = (const float*)d_in[2];
  const float* ln2w  = (const float*)d_in[3];
  const float* ln2b  = (const float*)d_in[4];
  const float* wqkv  = (const float*)d_in[5];
  const float* bqkv  = (const float*)d_in[6];
  const float* wo    = (const float*)d_in[7];
  const float* bo    = (const float*)d_in[8];
  const float* wgate = (const float*)d_in[9];
  const float* w1    = (const float*)d_in[10];
  const float* b1    = (const float*)d_in[11];
  const float* w2    = (const float*)d_in[12];
  const float* b2    = (const float*)d_in[13];

  // Workspace map (121 MB peak, lifetimes disjoint — see round-2 notes):
  char* ws = (char*)d_ws;
  const size_t MB = 1024 * 1024;
  float*    hbuf  = (float*)(ws + 0 * MB);
  ushort_t* ln1hi = (ushort_t*)(ws + 0 * MB);
  ushort_t* ln1lo = (ushort_t*)(ws + 4 * MB);
  float*    accb  = (float*)(ws + 8 * MB);
  ushort_t* wqkvThi = (ushort_t*)(ws + 8 * MB);             // 6 MB
  ushort_t* wqkvTlo = (ushort_t*)(ws + 14 * MB);            // 6 MB
  ushort_t* ln2bf = (ushort_t*)(ws + 16 * MB);              // 4 MB
  ushort_t* h1e   = (ushort_t*)(ws + 20 * MB);              // 32 MB
  float*    qkv   = (float*)(ws + 20 * MB);                 // 24 MB
  float*    ln2f  = (float*)(ws + 24 * MB);                 // 8 MB
  ushort_t* ctxhi = (ushort_t*)(ws + 44 * MB);
  ushort_t* ctxlo = (ushort_t*)(ws + 48 * MB);
  ushort_t* woThi = (ushort_t*)(ws + 52 * MB);              // 2 MB
  ushort_t* woTlo = (ushort_t*)(ws + 54 * MB);              // 2 MB
  float*    sc    = (float*)(ws + 56 * MB);                 // 64 MB
  ushort_t* wTe   = (ushort_t*)(ws + 56 * MB);              // 64 MB
  float*    webuf = (float*)(ws + 120 * MB);                // 64 KB
  int*      cnt   = (int*)  (ws + 120 * MB + 256 * 1024);   // 32 B
  int*      off   = (int*)  (ws + 120 * MB + 260 * 1024);   // 32 B
  int*      table = (int*)  (ws + 120 * MB + 264 * 1024);   // 256 B
  int*      bidx  = (int*)  (ws + 120 * MB + 320 * 1024);   // 64 KB
  float*    bw    = (float*)(ws + 120 * MB + 448 * 1024);   // 64 KB

  // ---- attention path: split-bf16 MFMA GEMMs (near-f32 accuracy) ----
  ln_k<2><<<N_TOK, 256, 0, stream>>>(x, ln1w, ln1b, nullptr, ln1hi, ln1lo);
  convT2<<<dim3(D3 / 64, DIM / 64), 256, 0, stream>>>(wqkv, wqkvThi, wqkvTlo, DIM, D3);
  gemm_split<0><<<(N_TOK / TBM) * (D3 / TBN), 256, 0, stream>>>(
      ln1hi, ln1lo, wqkvThi, wqkvTlo, bqkv, qkv, nullptr, D3, DIM, N_TOK / TBM);
  scores_k<<<dim3(8, 8, 64), 256, 0, stream>>>(qkv, sc);
  softmax_k<<<64 * TT, 256, 0, stream>>>(sc);
  ctx_k<<<dim3(8, 64), 256, 0, stream>>>(sc, qkv, ctxhi, ctxlo);
  // sc dead -> convert ALL expert w1 into wTe (one launch)
  convT_g<<<dim3(HID / 64, DIM / 64, NEXP), 256, 0, stream>>>(w1, wTe, DIM, HID);
  convT2<<<dim3(DIM / 64, DIM / 64), 256, 0, stream>>>(wo, woThi, woTlo, DIM, DIM);
  gemm_split<1><<<(N_TOK / TBM) * (DIM / TBN), 256, 0, stream>>>(
      ctxhi, ctxlo, woThi, woTlo, bo, hbuf, x, DIM, DIM, N_TOK / TBM);
  ln_k<1><<<N_TOK, 256, 0, stream>>>(hbuf, ln2w, ln2b, ln2f, ln2bf, nullptr);
  gate_k<<<N_TOK / 4, 256, 0, stream>>>(ln2f, wgate, webuf);

  // ---- routed MoE: dense slot-table grouped GEMMs ----
  hipMemsetAsync(cnt, 0, 32, stream);
  hipMemsetAsync(accb, 0, (size_t)N_TOK * DIM * 4, stream);
  route_k<<<N_TOK / 256, 256, 0, stream>>>(webuf, cnt, bidx, bw);
  plan_k<<<1, 64, 0, stream>>>(cnt, off, table);
  // GEMM1: 32 cols x <=40 dense row-slots
  moe_gemm_g<0><<<dim3(HID / TBN, 40), 256, 0, stream>>>(
      ln2bf, wTe, b1, h1e, nullptr, bidx, bw, cnt, off, table, HID);
  convT_g<<<dim3(DIM / 64, HID / 64, NEXP), 256, 0, stream>>>(w2, wTe, HID, DIM);
  // GEMM2: (8 cols x 4 ksplit) x <=40 dense row-slots
  moe_gemm_g<1><<<dim3(32, 40), 256, 0, stream>>>(
      h1e, wTe, b2, nullptr, accb, bidx, bw, cnt, off, table, DIM);
  final_k<<<(N_TOK * DIM) / 256, 256, 0, stream>>>(hbuf, accb, (float*)d_out);
}